// Round 8
// baseline (106.697 us; speedup 1.0000x reference)
//
#include <hip/hip_runtime.h>

// Problem dims
#define NZ 128
#define NY 192
#define NXP 193
#define NX 192
#define NVOX (NZ * NY * NX)
#define NZ0 (NZ * NY)      // 24576

// Tile: 32 x 16 xy outputs per block (2 chains/thread at y, y+8), 4 z-outputs
// TZ=4 (was 8): doubles block count -> ~9.4 blocks/CU so the wave cap, not
// the grid, bounds occupancy (R7 post-mortem: 23% occupancy was grid-limited).
#define TX 32
#define TY 16
#define TZ 4
#define LX 34              // TX + 2
#define LY 18              // TY + 2
#define LZ 6               // TZ + 2
#define LSL (LY * LX)      // 612 floats per z-slice
#define LTOT (LZ * LSL)    // 3672 floats = 14688 B -> ~8 blocks/CU by LDS

#define GX (NX / TX)       // 6
#define GY (NY / TY)       // 12
#define GZ (NZ / TZ)       // 32
#define NBLK (GX * GY * GZ) // 2304
#define ZB (NZ0 / 256)     // 96 z0-gather blocks (dispatched first)

// Device-global scratch. Lifecycle: g_hist is zero at entry to every call
// (zero-init at load; re-zeroed by final_k), g_ps/g_pm/g_u are fully
// overwritten every call before being read.
__device__ double   g_ps[NBLK];
__device__ float    g_pm[NBLK];
__device__ unsigned g_hist[2048];
__device__ unsigned g_u[NZ0];

__device__ __forceinline__ int refl(int i, int n) {
    i = (i < 0) ? -i : i;
    i = (i >= n) ? (2 * n - 2 - i) : i;
    return i;
}

__device__ __forceinline__ unsigned f2sortable(float f) {
    unsigned bits = __float_as_uint(f);
    return bits ^ ((bits & 0x80000000u) ? 0xFFFFFFFFu : 0x80000000u);
}

// ---- Batcher odd-even merge / sort (verified rounds 2-7, absmax 0) ----
template<int M, int N>
struct OEM {
    static __device__ __forceinline__ void run(const float* a, const float* b, float* out) {
        if constexpr (M == 0) {
#pragma unroll
            for (int i = 0; i < N; ++i) out[i] = b[i];
        } else if constexpr (N == 0) {
#pragma unroll
            for (int i = 0; i < M; ++i) out[i] = a[i];
        } else if constexpr (M == 1 && N == 1) {
            out[0] = fminf(a[0], b[0]);
            out[1] = fmaxf(a[0], b[0]);
        } else {
            constexpr int ME = (M + 1) / 2, MO = M / 2, NE = (N + 1) / 2, NO = N / 2;
            float ae[ME], be[NE];
            float ao[MO > 0 ? MO : 1], bo[NO > 0 ? NO : 1];
#pragma unroll
            for (int i = 0; i < ME; ++i) ae[i] = a[2 * i];
#pragma unroll
            for (int i = 0; i < MO; ++i) ao[i] = a[2 * i + 1];
#pragma unroll
            for (int i = 0; i < NE; ++i) be[i] = b[2 * i];
#pragma unroll
            for (int i = 0; i < NO; ++i) bo[i] = b[2 * i + 1];
            constexpr int EL = ME + NE, OL = MO + NO;
            float e[EL];
            float o[OL > 0 ? OL : 1];
            OEM<ME, NE>::run(ae, be, e);
            OEM<MO, NO>::run(ao, bo, o);
            constexpr int P = (OL < EL - 1) ? OL : (EL - 1);
            out[0] = e[0];
#pragma unroll
            for (int i = 0; i < P; ++i) {
                out[2 * i + 1] = fminf(o[i], e[i + 1]);
                out[2 * i + 2] = fmaxf(o[i], e[i + 1]);
            }
            if constexpr (EL == OL)           out[M + N - 1] = o[OL - 1];
            else if constexpr (EL == OL + 2)  out[M + N - 1] = e[EL - 1];
        }
    }
};

template<int N>
struct OES {
    static __device__ __forceinline__ void run(const float* in, float* out) {
        if constexpr (N == 1) {
            out[0] = in[0];
        } else {
            constexpr int H = N / 2;
            float s1[H], s2[N - H];
            OES<H>::run(in, s1);
            OES<N - H>::run(in + H, s2);
            OEM<H, N - H>::run(s1, s2, out);
        }
    }
};

// med27 = min( M[13], min_i max(A[i], M[12-i]) ), tree-shaped (depth ~5)
__device__ __forceinline__ float sel27(const float* A, const float* M) {
    float t0 = fmaxf(A[0], M[12]);
    float t1 = fmaxf(A[1], M[11]);
    float t2 = fmaxf(A[2], M[10]);
    float t3 = fmaxf(A[3], M[9]);
    float t4 = fmaxf(A[4], M[8]);
    float t5 = fmaxf(A[5], M[7]);
    float t6 = fmaxf(A[6], M[6]);
    float t7 = fmaxf(A[7], M[5]);
    float t8 = fmaxf(A[8], M[4]);
    float r0 = fminf(fminf(t0, t1), fminf(t2, t3));
    float r1 = fminf(fminf(t4, t5), fminf(t6, t7));
    return fminf(fminf(r0, r1), fminf(t8, M[13]));
}

// Fused: blocks 0..ZB-1 gather z0 + build global histogram (overlap with
// loss tiles, blocks ZB..ZB+NBLK-1).
__global__ __launch_bounds__(256, 4) void fused_main(const float* __restrict__ P) {
    __shared__ float dt[LTOT];
    const int tid = threadIdx.x;
    const int bid = blockIdx.x;

    if (bid < ZB) {
        // ---- z0 gather + histogram role ----
        unsigned* h = (unsigned*)dt;
        for (int j = tid; j < 2048; j += 256) h[j] = 0u;
        __syncthreads();
        const int i = bid * 256 + tid;
        unsigned u = f2sortable(P[(size_t)i * NXP]);
        g_u[i] = u;
        atomicAdd(&h[u >> 21], 1u);
        __syncthreads();
        for (int j = tid; j < 2048; j += 256) {
            unsigned c = h[j];
            if (c) atomicAdd(&g_hist[j], c);
        }
        return;
    }

    // ---- loss tile role ----
    const int bf = bid - ZB;
    const int bx = bf % GX;
    const int brem = bf / GX;
    const int by = brem % GY;
    const int bz = brem / GY;
    const int x0 = bx * TX, y0 = by * TY, z0t = bz * TZ;

    // Stage d-tile (reflect halo) into LDS; div/mod hoisted out of zz loop.
    int goff[3], lp[3];
#pragma unroll
    for (int k = 0; k < 3; ++k) {
        int p = tid + 256 * k;
        lp[k] = (p < LSL) ? p : -1;
        if (p < LSL) {
            int xx = p % LX, yy = p / LX;
            int gy = refl(y0 + yy - 1, NY);
            int gx = refl(x0 + xx - 1, NX);
            goff[k] = gy * NXP + gx;
        }
    }
    for (int zz = 0; zz < LZ; ++zz) {
        int gz = refl(z0t + zz - 1, NZ);
        const float* __restrict__ pl = P + (size_t)gz * (NY * NXP);
#pragma unroll
        for (int k = 0; k < 3; ++k) {
            if (lp[k] >= 0) {
                float a = pl[goff[k]];
                float b = pl[goff[k] + 1];
                dt[zz * LSL + lp[k]] = b - a;
            }
        }
    }
    __syncthreads();

    const int x = tid & 31;
    const int y = tid >> 5;             // 0..7; chains at y and y+8
    const int lbA = y * LX + x;
    const int lbB = lbA + 8 * LX;

    auto rd9 = [&](int base, float* v) {
#pragma unroll
        for (int dy = 0; dy < 3; ++dy)
#pragma unroll
            for (int dxx = 0; dxx < 3; ++dxx)
                v[dy * 3 + dxx] = dt[base + dy * LX + dxx];
    };

    float SA0[9], SA1[9], SA2[9], SB0[9], SB1[9], SB2[9];
    float P0a[9], P0b[9], P1a[9], P1b[9];     // ping-pong LDS preload buffers
    float cA, cB, s_acc = 0.0f, m_acc = 0.0f;

    {
        rd9(lbA, P0a);            rd9(lbB, P0b);
        OES<9>::run(P0a, SA0);    OES<9>::run(P0b, SB0);
        rd9(lbA + LSL, P1a);      rd9(lbB + LSL, P1b);
        cA = P1a[4];              cB = P1b[4];
        OES<9>::run(P1a, SA1);    OES<9>::run(P1b, SB1);
        rd9(lbA + 2 * LSL, P0a);  rd9(lbB + 2 * LSL, P0b);   // preload slice 2
    }

    // One pair = 2 z-steps; roles rotate (X=oldest, Y=mid, Z=new slot).
    auto pairstep = [&](float (&XA)[9], float (&YA)[9], float (&ZA)[9],
                        float (&XB)[9], float (&YB)[9], float (&ZB_)[9], int t) {
        float MA[18], MB[18];
        // even step t: consumes P0 = slice t+2; prefetch slice t+3 -> P1
        float cnA = P0a[4], cnB = P0b[4];
        rd9(lbA + (t + 3) * LSL, P1a);
        rd9(lbB + (t + 3) * LSL, P1b);
        OES<9>::run(P0a, ZA);           OES<9>::run(P0b, ZB_);
        OEM<9, 9>::run(YA, ZA, MA);     OEM<9, 9>::run(YB, ZB_, MB);
        float medA = sel27(XA, MA), medB = sel27(XB, MB);
        float dA = cA - medA, dB = cB - medB;
        s_acc = fmaf(dA, dA, fmaf(dB, dB, s_acc));
        m_acc = fmaxf(m_acc, fmaxf(1.0f - cA, 1.0f - cB));
        cA = cnA; cB = cnB;
        // odd step t+1: consumes P1 = slice t+3; prefetch slice t+4 -> P0
        cnA = P1a[4]; cnB = P1b[4];
        if (t < TZ - 2) {
            rd9(lbA + (t + 4) * LSL, P0a);
            rd9(lbB + (t + 4) * LSL, P0b);
        }
        OES<9>::run(P1a, XA);           OES<9>::run(P1b, XB);
        medA = sel27(XA, MA);           medB = sel27(XB, MB);
        dA = cA - medA; dB = cB - medB;
        s_acc = fmaf(dA, dA, fmaf(dB, dB, s_acc));
        m_acc = fmaxf(m_acc, fmaxf(1.0f - cA, 1.0f - cB));
        cA = cnA; cB = cnB;
    };

    // Rotation: after a pair, oldest=Z, mid=X, spare=Y  =>  (X,Y,Z)->(Z,X,Y)
    pairstep(SA0, SA1, SA2, SB0, SB1, SB2, 0);
    pairstep(SA2, SA0, SA1, SB2, SB0, SB1, 2);

    // Block reduction -> per-block partial (plain stores, no atomics).
#pragma unroll
    for (int off = 32; off > 0; off >>= 1) {
        s_acc += __shfl_down(s_acc, off);
        m_acc = fmaxf(m_acc, __shfl_down(m_acc, off));
    }
    __shared__ float ss[4], sm[4];
    const int lane = tid & 63, wid = tid >> 6;
    if (lane == 0) { ss[wid] = s_acc; sm[wid] = m_acc; }
    __syncthreads();
    if (tid == 0) {
        float S = (ss[0] + ss[1]) + (ss[2] + ss[3]);
        float M = fmaxf(fmaxf(sm[0], sm[1]), fmaxf(sm[2], sm[3]));
        g_ps[bf] = (double)S;
        g_pm[bf] = M;
    }
}

// Bucket-pick from g_hist + candidate counting-select + partial reduction.
// Re-zeroes g_hist at the end for the next call (graph-safe lifecycle).
__global__ __launch_bounds__(1024) void final_k(float* __restrict__ out) {
    __shared__ unsigned cand[2048];      // candidates, or radix hist (fallback)
    __shared__ unsigned s_cnt, s_med, s_b, s_r;
    __shared__ unsigned wsum[16], woff[16];
    const int tid = threadIdx.x;
    const int lane = tid & 63, wid = tid >> 6;
    const unsigned kk = (NZ0 - 1) / 2;   // 12287

    // ---- 1. pick the top-11-bit bucket containing rank kk ----
    unsigned h0 = g_hist[2 * tid], h1 = g_hist[2 * tid + 1];
    {
        unsigned mysum = h0 + h1, inc = mysum;
#pragma unroll
        for (int d = 1; d < 64; d <<= 1) { unsigned t2 = __shfl_up(inc, d); if (lane >= d) inc += t2; }
        if (lane == 63) wsum[wid] = inc;
        __syncthreads();
        if (tid == 0) { unsigned a = 0; for (int w = 0; w < 16; ++w) { woff[w] = a; a += wsum[w]; } }
        __syncthreads();
        unsigned exc = woff[wid] + inc - mysum;
        if (exc <= kk && kk < exc + h0) { s_b = 2u * tid; s_r = kk - exc; }
        exc += h0;
        if (exc <= kk && kk < exc + h1) { s_b = 2u * tid + 1u; s_r = kk - exc; }
    }
    __syncthreads();
    const unsigned b1 = s_b, k1 = s_r;
    // re-zero g_hist for the next call (values already consumed into regs)
    g_hist[2 * tid] = 0u; g_hist[2 * tid + 1] = 0u;

    // ---- 2. gather in-bucket candidates, exact counting-select ----
    if (tid == 0) s_cnt = 0u;
    __syncthreads();
    for (int i = tid; i < NZ0; i += 1024) {
        unsigned u = g_u[i];
        if ((u >> 21) == b1) {
            unsigned idx = atomicAdd(&s_cnt, 1u);
            if (idx < 2048u) cand[idx] = u;
        }
    }
    __syncthreads();
    const unsigned m = s_cnt;

    if (m <= 2048u) {
        for (int i = tid; i < (int)m; i += 1024) {
            unsigned c = cand[i], less = 0u, eq = 0u;
            for (unsigned j = 0; j < m; ++j) {
                unsigned v = cand[j];
                less += (v < c); eq += (v == c);
            }
            if (less <= k1 && k1 < less + eq) s_med = c;
        }
        __syncthreads();
    } else {
        // fallback: 11-bit + 10-bit radix passes over g_u (filtered)
        unsigned pref = b1, kx = k1;
        for (int j = tid; j < 2048; j += 1024) cand[j] = 0u;
        __syncthreads();
        for (int i = tid; i < NZ0; i += 1024) {
            unsigned u = g_u[i];
            if ((u >> 21) == pref) atomicAdd(&cand[(u >> 10) & 2047u], 1u);
        }
        __syncthreads();
        {
            unsigned c0 = cand[tid * 2], c1 = cand[tid * 2 + 1];
            unsigned mysum = c0 + c1, inc = mysum;
#pragma unroll
            for (int d = 1; d < 64; d <<= 1) { unsigned t2 = __shfl_up(inc, d); if (lane >= d) inc += t2; }
            if (lane == 63) wsum[wid] = inc;
            __syncthreads();
            if (tid == 0) { unsigned a = 0; for (int w = 0; w < 16; ++w) { woff[w] = a; a += wsum[w]; } }
            __syncthreads();
            unsigned exc = woff[wid] + inc - mysum;
            if (exc <= kx && kx < exc + c0) { s_b = tid * 2u; s_r = kx - exc; }
            exc += c0;
            if (exc <= kx && kx < exc + c1) { s_b = tid * 2u + 1u; s_r = kx - exc; }
        }
        __syncthreads();
        pref = (pref << 11) | s_b; kx = s_r;
        __syncthreads();
        for (int j = tid; j < 1024; j += 1024) cand[j] = 0u;
        __syncthreads();
        for (int i = tid; i < NZ0; i += 1024) {
            unsigned u = g_u[i];
            if ((u >> 10) == pref) atomicAdd(&cand[u & 1023u], 1u);
        }
        __syncthreads();
        {
            unsigned c0 = cand[tid], mysum = c0, inc = mysum;
#pragma unroll
            for (int d = 1; d < 64; d <<= 1) { unsigned t2 = __shfl_up(inc, d); if (lane >= d) inc += t2; }
            if (lane == 63) wsum[wid] = inc;
            __syncthreads();
            if (tid == 0) { unsigned a = 0; for (int w = 0; w < 16; ++w) { woff[w] = a; a += wsum[w]; } }
            __syncthreads();
            unsigned exc = woff[wid] + inc - mysum;
            if (exc <= kx && kx < exc + c0) s_b = (unsigned)tid;
        }
        __syncthreads();
        if (tid == 0) s_med = (pref << 10) | s_b;
        __syncthreads();
    }

    // ---- 3. reduce the NBLK per-block partials (fixed deterministic order) ----
    double s = 0.0; float mm = 0.0f;
    for (int i = tid; i < NBLK; i += 1024) {
        s += g_ps[i];
        mm = fmaxf(mm, g_pm[i]);
    }
#pragma unroll
    for (int off = 32; off > 0; off >>= 1) {
        s += __shfl_down(s, off);
        mm = fmaxf(mm, __shfl_down(mm, off));
    }
    __shared__ double sd[16];
    __shared__ float sf[16];
    if (lane == 0) { sd[wid] = s; sf[wid] = mm; }
    __syncthreads();
    if (tid == 0) {
        double S = 0.0; float M = 0.0f;
        for (int w = 0; w < 16; ++w) { S += sd[w]; M = fmaxf(M, sf[w]); }
        unsigned u = s_med;
        unsigned bits = (u & 0x80000000u) ? (u ^ 0x80000000u) : ~u;
        float med = __uint_as_float(bits);
        out[0] = (float)(S / (double)NVOX);
        out[1] = M;
        out[2] = med * med;
    }
}

extern "C" void kernel_launch(void* const* d_in, const int* in_sizes, int n_in,
                              void* d_out, int out_size, void* d_ws, size_t ws_size,
                              hipStream_t stream) {
    const float* P = (const float*)d_in[0];
    float* out = (float*)d_out;

    hipLaunchKernelGGL(fused_main, dim3(ZB + NBLK), dim3(256), 0, stream, P);
    hipLaunchKernelGGL(final_k, dim3(1), dim3(1024), 0, stream, out);
}

// Round 10
// 95.738 us; speedup vs baseline: 1.1145x; 1.1145x over previous
//
#include <hip/hip_runtime.h>

// Problem dims
#define NZ 128
#define NY 192
#define NXP 193
#define NX 192
#define NVOX (NZ * NY * NX)
#define NZ0 (NZ * NY)      // 24576

// Tile: 32 x 16 xy outputs per block, 8 z-outputs per thread.
// The two y-chains (y, y+8) are PACKED into the two f16 lanes of a native
// _Float16x2 vector: LDS entry (z, r, x) = { d[z][y0+r-1][x], d[z][y0+r+7][x] }
// so one packed sort network + one packed ds_read serves both chains
// (R8 post-mortem: kernel is issue-throughput bound; packing halves ops).
#define TX 32
#define TY 16
#define TZ 8
#define LX 34              // TX + 2
#define LYP 10             // packed rows r=0..9 (low: d rows -1..8, high: 7..16)
#define LZ 10              // TZ + 2
#define LSLP (LYP * LX)    // 340 packed entries per z-slice
#define LTOTP (LZ * LSLP)  // 3400 half2 = 13600 B

#define GX (NX / TX)       // 6
#define GY (NY / TY)       // 12
#define GZ (NZ / TZ)       // 16
#define NBLK (GX * GY * GZ) // 1152
#define ZB (NZ0 / 256)     // 96 z0-gather blocks (dispatched first)

// Device-global scratch. Lifecycle: g_hist is zero at entry to every call
// (zero-init at load; re-zeroed by final_k), g_ps/g_pm/g_u fully overwritten
// every call before being read.
__device__ double   g_ps[NBLK];
__device__ float    g_pm[NBLK];
__device__ unsigned g_hist[2048];
__device__ unsigned g_u[NZ0];

__device__ __forceinline__ int refl(int i, int n) {
    i = (i < 0) ? -i : i;
    i = (i >= n) ? (2 * n - 2 - i) : i;
    return i;
}

__device__ __forceinline__ unsigned f2sortable(float f) {
    unsigned bits = __float_as_uint(f);
    return bits ^ ((bits & 0x80000000u) ? 0xFFFFFFFFu : 0x80000000u);
}

// Native packed f16 pair: clang ext vector, no hip_fp16.h API dependence.
// __builtin_elementwise_min/max lower to v_pk_min_f16 / v_pk_max_f16.
typedef _Float16 H2 __attribute__((ext_vector_type(2)));

static __device__ __forceinline__ H2 h2min(H2 a, H2 b) { return __builtin_elementwise_min(a, b); }
static __device__ __forceinline__ H2 h2max(H2 a, H2 b) { return __builtin_elementwise_max(a, b); }

// ---- Batcher odd-even merge / sort on packed pairs (network topology
// verified rounds 2-8 at absmax 0 in f32; ops now packed f16) ----
template<int M, int N>
struct OEM {
    static __device__ __forceinline__ void run(const H2* a, const H2* b, H2* out) {
        if constexpr (M == 0) {
#pragma unroll
            for (int i = 0; i < N; ++i) out[i] = b[i];
        } else if constexpr (N == 0) {
#pragma unroll
            for (int i = 0; i < M; ++i) out[i] = a[i];
        } else if constexpr (M == 1 && N == 1) {
            out[0] = h2min(a[0], b[0]);
            out[1] = h2max(a[0], b[0]);
        } else {
            constexpr int ME = (M + 1) / 2, MO = M / 2, NE = (N + 1) / 2, NO = N / 2;
            H2 ae[ME], be[NE];
            H2 ao[MO > 0 ? MO : 1], bo[NO > 0 ? NO : 1];
#pragma unroll
            for (int i = 0; i < ME; ++i) ae[i] = a[2 * i];
#pragma unroll
            for (int i = 0; i < MO; ++i) ao[i] = a[2 * i + 1];
#pragma unroll
            for (int i = 0; i < NE; ++i) be[i] = b[2 * i];
#pragma unroll
            for (int i = 0; i < NO; ++i) bo[i] = b[2 * i + 1];
            constexpr int EL = ME + NE, OL = MO + NO;
            H2 e[EL];
            H2 o[OL > 0 ? OL : 1];
            OEM<ME, NE>::run(ae, be, e);
            OEM<MO, NO>::run(ao, bo, o);
            constexpr int P = (OL < EL - 1) ? OL : (EL - 1);
            out[0] = e[0];
#pragma unroll
            for (int i = 0; i < P; ++i) {
                out[2 * i + 1] = h2min(o[i], e[i + 1]);
                out[2 * i + 2] = h2max(o[i], e[i + 1]);
            }
            if constexpr (EL == OL)           out[M + N - 1] = o[OL - 1];
            else if constexpr (EL == OL + 2)  out[M + N - 1] = e[EL - 1];
        }
    }
};

template<int N>
struct OES {
    static __device__ __forceinline__ void run(const H2* in, H2* out) {
        if constexpr (N == 1) {
            out[0] = in[0];
        } else {
            constexpr int H = N / 2;
            H2 s1[H], s2[N - H];
            OES<H>::run(in, s1);
            OES<N - H>::run(in + H, s2);
            OEM<H, N - H>::run(s1, s2, out);
        }
    }
};

// med27 = min( M[13], min_i max(A[i], M[12-i]) ), packed over both chains
__device__ __forceinline__ H2 sel27(const H2* A, const H2* M) {
    H2 t0 = h2max(A[0], M[12]);
    H2 t1 = h2max(A[1], M[11]);
    H2 t2 = h2max(A[2], M[10]);
    H2 t3 = h2max(A[3], M[9]);
    H2 t4 = h2max(A[4], M[8]);
    H2 t5 = h2max(A[5], M[7]);
    H2 t6 = h2max(A[6], M[6]);
    H2 t7 = h2max(A[7], M[5]);
    H2 t8 = h2max(A[8], M[4]);
    H2 r0 = h2min(h2min(t0, t1), h2min(t2, t3));
    H2 r1 = h2min(h2min(t4, t5), h2min(t6, t7));
    return h2min(h2min(r0, r1), h2min(t8, M[13]));
}

// Fused: blocks 0..ZB-1 gather z0 + build global histogram (overlap with
// loss tiles, blocks ZB..ZB+NBLK-1).
__global__ __launch_bounds__(256, 4) void fused_main(const float* __restrict__ P) {
    __shared__ H2 dt[LTOTP];
    const int tid = threadIdx.x;
    const int bid = blockIdx.x;

    if (bid < ZB) {
        // ---- z0 gather + histogram role (exact f32 path, untouched) ----
        unsigned* h = (unsigned*)dt;
        for (int j = tid; j < 2048; j += 256) h[j] = 0u;
        __syncthreads();
        const int i = bid * 256 + tid;
        unsigned u = f2sortable(P[(size_t)i * NXP]);
        g_u[i] = u;
        atomicAdd(&h[u >> 21], 1u);
        __syncthreads();
        for (int j = tid; j < 2048; j += 256) {
            unsigned c = h[j];
            if (c) atomicAdd(&g_hist[j], c);
        }
        return;
    }

    // ---- loss tile role ----
    const int bf = bid - ZB;
    const int bx = bf % GX;
    const int brem = bf / GX;
    const int by = brem % GY;
    const int bz = brem / GY;
    const int x0 = bx * TX, y0 = by * TY, z0t = bz * TZ;

    // Stage packed d-tile into LDS. Entry p: xx = p%LX, rr = p/LX; low half
    // from d row y0+rr-1, high half from d row y0+rr+7 (both reflect-mapped).
    int offL[2], offH[2], lp[2];
#pragma unroll
    for (int k = 0; k < 2; ++k) {
        int p = tid + 256 * k;
        lp[k] = (p < LSLP) ? p : -1;
        if (p < LSLP) {
            int xx = p % LX, rr = p / LX;
            int gx  = refl(x0 + xx - 1, NX);
            int gyL = refl(y0 + rr - 1, NY);
            int gyH = refl(y0 + rr + 7, NY);
            offL[k] = gyL * NXP + gx;
            offH[k] = gyH * NXP + gx;
        }
    }
    for (int zz = 0; zz < LZ; ++zz) {
        int gz = refl(z0t + zz - 1, NZ);
        const float* __restrict__ pl = P + (size_t)gz * (NY * NXP);
#pragma unroll
        for (int k = 0; k < 2; ++k) {
            if (lp[k] >= 0) {
                float dL = pl[offL[k] + 1] - pl[offL[k]];
                float dH = pl[offH[k] + 1] - pl[offH[k]];
                H2 v;
                v.x = (_Float16)dL;
                v.y = (_Float16)dH;
                dt[zz * LSLP + lp[k]] = v;
            }
        }
    }
    __syncthreads();

    const int x = tid & 31;
    const int y = tid >> 5;            // 0..7; packed rows y..y+2 serve y and y+8
    const int rbase = y * LX + x;

    auto rd9 = [&](int base, H2* v) {
#pragma unroll
        for (int dy = 0; dy < 3; ++dy)
#pragma unroll
            for (int dxx = 0; dxx < 3; ++dxx)
                v[dy * 3 + dxx] = dt[base + dy * LX + dxx];
    };

    H2 S0[9], S1[9], S2[9];
    H2 P0[9], P1[9];                   // ping-pong LDS preload buffers
    H2 c2, m2 = (H2)((_Float16)0.0f);
    const H2 one2 = (H2)((_Float16)1.0f);
    float s_acc = 0.0f;

    {
        rd9(rbase, P0);
        OES<9>::run(P0, S0);
        rd9(rbase + LSLP, P1);
        c2 = P1[4];
        OES<9>::run(P1, S1);
        rd9(rbase + 2 * LSLP, P0);     // preload slice 2
    }

    auto accum = [&](H2 med) {
        H2 df = c2 - med;
        float dl = (float)df.x, dh = (float)df.y;
        s_acc = fmaf(dl, dl, fmaf(dh, dh, s_acc));
        m2 = h2max(m2, one2 - c2);
    };

    // One pair = 2 z-steps; roles rotate (X=oldest, Y=mid, Z=new slot).
    auto pairstep = [&](H2 (&X)[9], H2 (&Y)[9], H2 (&Z)[9], int t) {
        H2 M[18];
        // even step t: consumes P0 = slice t+2; prefetch slice t+3 -> P1
        H2 cn = P0[4];
        rd9(rbase + (t + 3) * LSLP, P1);
        OES<9>::run(P0, Z);
        OEM<9, 9>::run(Y, Z, M);
        accum(sel27(X, M));
        c2 = cn;
        // odd step t+1: consumes P1 = slice t+3; prefetch slice t+4 -> P0
        cn = P1[4];
        if (t < TZ - 2) rd9(rbase + (t + 4) * LSLP, P0);
        OES<9>::run(P1, X);
        accum(sel27(X, M));
        c2 = cn;
    };

    // Rotation: after a pair, oldest=Z, mid=X, spare=Y  =>  (X,Y,Z)->(Z,X,Y)
    pairstep(S0, S1, S2, 0);
    pairstep(S2, S0, S1, 2);
    pairstep(S1, S2, S0, 4);
    pairstep(S0, S1, S2, 6);

    float m_acc = fmaxf((float)m2.x, (float)m2.y);

    // Block reduction -> per-block partial (plain stores, no atomics).
#pragma unroll
    for (int off = 32; off > 0; off >>= 1) {
        s_acc += __shfl_down(s_acc, off);
        m_acc = fmaxf(m_acc, __shfl_down(m_acc, off));
    }
    __shared__ float ss[4], sm[4];
    const int lane = tid & 63, wid = tid >> 6;
    if (lane == 0) { ss[wid] = s_acc; sm[wid] = m_acc; }
    __syncthreads();
    if (tid == 0) {
        float S = (ss[0] + ss[1]) + (ss[2] + ss[3]);
        float M = fmaxf(fmaxf(sm[0], sm[1]), fmaxf(sm[2], sm[3]));
        g_ps[bf] = (double)S;
        g_pm[bf] = M;
    }
}

// Bucket-pick from g_hist + candidate counting-select + partial reduction.
// Re-zeroes g_hist at the end for the next call (graph-safe lifecycle).
__global__ __launch_bounds__(1024) void final_k(float* __restrict__ out) {
    __shared__ unsigned cand[2048];      // candidates, or radix hist (fallback)
    __shared__ unsigned s_cnt, s_med, s_b, s_r;
    __shared__ unsigned wsum[16], woff[16];
    const int tid = threadIdx.x;
    const int lane = tid & 63, wid = tid >> 6;
    const unsigned kk = (NZ0 - 1) / 2;   // 12287

    // ---- 1. pick the top-11-bit bucket containing rank kk ----
    unsigned h0 = g_hist[2 * tid], h1 = g_hist[2 * tid + 1];
    {
        unsigned mysum = h0 + h1, inc = mysum;
#pragma unroll
        for (int d = 1; d < 64; d <<= 1) { unsigned t2 = __shfl_up(inc, d); if (lane >= d) inc += t2; }
        if (lane == 63) wsum[wid] = inc;
        __syncthreads();
        if (tid == 0) { unsigned a = 0; for (int w = 0; w < 16; ++w) { woff[w] = a; a += wsum[w]; } }
        __syncthreads();
        unsigned exc = woff[wid] + inc - mysum;
        if (exc <= kk && kk < exc + h0) { s_b = 2u * tid; s_r = kk - exc; }
        exc += h0;
        if (exc <= kk && kk < exc + h1) { s_b = 2u * tid + 1u; s_r = kk - exc; }
    }
    __syncthreads();
    const unsigned b1 = s_b, k1 = s_r;
    // re-zero g_hist for the next call (values already consumed into regs)
    g_hist[2 * tid] = 0u; g_hist[2 * tid + 1] = 0u;

    // ---- 2. gather in-bucket candidates, exact counting-select ----
    if (tid == 0) s_cnt = 0u;
    __syncthreads();
    for (int i = tid; i < NZ0; i += 1024) {
        unsigned u = g_u[i];
        if ((u >> 21) == b1) {
            unsigned idx = atomicAdd(&s_cnt, 1u);
            if (idx < 2048u) cand[idx] = u;
        }
    }
    __syncthreads();
    const unsigned m = s_cnt;

    if (m <= 2048u) {
        for (int i = tid; i < (int)m; i += 1024) {
            unsigned c = cand[i], less = 0u, eq = 0u;
            for (unsigned j = 0; j < m; ++j) {
                unsigned v = cand[j];
                less += (v < c); eq += (v == c);
            }
            if (less <= k1 && k1 < less + eq) s_med = c;
        }
        __syncthreads();
    } else {
        // fallback: 11-bit + 10-bit radix passes over g_u (filtered)
        unsigned pref = b1, kx = k1;
        for (int j = tid; j < 2048; j += 1024) cand[j] = 0u;
        __syncthreads();
        for (int i = tid; i < NZ0; i += 1024) {
            unsigned u = g_u[i];
            if ((u >> 21) == pref) atomicAdd(&cand[(u >> 10) & 2047u], 1u);
        }
        __syncthreads();
        {
            unsigned c0 = cand[tid * 2], c1 = cand[tid * 2 + 1];
            unsigned mysum = c0 + c1, inc = mysum;
#pragma unroll
            for (int d = 1; d < 64; d <<= 1) { unsigned t2 = __shfl_up(inc, d); if (lane >= d) inc += t2; }
            if (lane == 63) wsum[wid] = inc;
            __syncthreads();
            if (tid == 0) { unsigned a = 0; for (int w = 0; w < 16; ++w) { woff[w] = a; a += wsum[w]; } }
            __syncthreads();
            unsigned exc = woff[wid] + inc - mysum;
            if (exc <= kx && kx < exc + c0) { s_b = tid * 2u; s_r = kx - exc; }
            exc += c0;
            if (exc <= kx && kx < exc + c1) { s_b = tid * 2u + 1u; s_r = kx - exc; }
        }
        __syncthreads();
        pref = (pref << 11) | s_b; kx = s_r;
        __syncthreads();
        for (int j = tid; j < 1024; j += 1024) cand[j] = 0u;
        __syncthreads();
        for (int i = tid; i < NZ0; i += 1024) {
            unsigned u = g_u[i];
            if ((u >> 10) == pref) atomicAdd(&cand[u & 1023u], 1u);
        }
        __syncthreads();
        {
            unsigned c0 = cand[tid], mysum = c0, inc = mysum;
#pragma unroll
            for (int d = 1; d < 64; d <<= 1) { unsigned t2 = __shfl_up(inc, d); if (lane >= d) inc += t2; }
            if (lane == 63) wsum[wid] = inc;
            __syncthreads();
            if (tid == 0) { unsigned a = 0; for (int w = 0; w < 16; ++w) { woff[w] = a; a += wsum[w]; } }
            __syncthreads();
            unsigned exc = woff[wid] + inc - mysum;
            if (exc <= kx && kx < exc + c0) s_b = (unsigned)tid;
        }
        __syncthreads();
        if (tid == 0) s_med = (pref << 10) | s_b;
        __syncthreads();
    }

    // ---- 3. reduce the NBLK per-block partials (fixed deterministic order) ----
    double s = 0.0; float mm = 0.0f;
    for (int i = tid; i < NBLK; i += 1024) {
        s += g_ps[i];
        mm = fmaxf(mm, g_pm[i]);
    }
#pragma unroll
    for (int off = 32; off > 0; off >>= 1) {
        s += __shfl_down(s, off);
        mm = fmaxf(mm, __shfl_down(mm, off));
    }
    __shared__ double sd[16];
    __shared__ float sf[16];
    if (lane == 0) { sd[wid] = s; sf[wid] = mm; }
    __syncthreads();
    if (tid == 0) {
        double S = 0.0; float M = 0.0f;
        for (int w = 0; w < 16; ++w) { S += sd[w]; M = fmaxf(M, sf[w]); }
        unsigned u = s_med;
        unsigned bits = (u & 0x80000000u) ? (u ^ 0x80000000u) : ~u;
        float med = __uint_as_float(bits);
        out[0] = (float)(S / (double)NVOX);
        out[1] = M;
        out[2] = med * med;
    }
}

extern "C" void kernel_launch(void* const* d_in, const int* in_sizes, int n_in,
                              void* d_out, int out_size, void* d_ws, size_t ws_size,
                              hipStream_t stream) {
    const float* P = (const float*)d_in[0];
    float* out = (float*)d_out;

    hipLaunchKernelGGL(fused_main, dim3(ZB + NBLK), dim3(256), 0, stream, P);
    hipLaunchKernelGGL(final_k, dim3(1), dim3(1024), 0, stream, out);
}

// Round 11
// 94.929 us; speedup vs baseline: 1.1240x; 1.0085x over previous
//
#include <hip/hip_runtime.h>

// Problem dims
#define NZ 128
#define NY 192
#define NXP 193
#define NX 192
#define NVOX (NZ * NY * NX)
#define NZ0 (NZ * NY)      // 24576

// Tile: 32 x 16 xy outputs per block, 8 z-outputs per thread.
// Two y-chains (y, y+8) packed into the two f16 lanes of a native _Float16x2
// (R10: WIN, 104.5 -> 95.7). R11: the z-loop is NOT unrolled (single 2-step
// body + register rotation) to shrink I-footprint ~4x — theory: issue stalls
// are instruction-fetch/I$ bound (R8 more-waves neutral, R7 prefetch neutral,
// R2 small-body ran 73% VALUBusy vs 41% for all big-body variants).
#define TX 32
#define TY 16
#define TZ 8
#define LX 34              // TX + 2
#define LYP 10             // packed rows r=0..9 (low: d rows -1..8, high: 7..16)
#define LZ 10              // TZ + 2
#define LSLP (LYP * LX)    // 340 packed entries per z-slice
#define LTOTP (LZ * LSLP)  // 3400 half2 = 13600 B

#define GX (NX / TX)       // 6
#define GY (NY / TY)       // 12
#define GZ (NZ / TZ)       // 16
#define NBLK (GX * GY * GZ) // 1152
#define ZB (NZ0 / 256)     // 96 z0-gather blocks (dispatched first)

// Device-global scratch. Lifecycle: g_hist is zero at entry to every call
// (zero-init at load; re-zeroed by final_k), g_ps/g_pm/g_u fully overwritten
// every call before being read.
__device__ double   g_ps[NBLK];
__device__ float    g_pm[NBLK];
__device__ unsigned g_hist[2048];
__device__ unsigned g_u[NZ0];

__device__ __forceinline__ int refl(int i, int n) {
    i = (i < 0) ? -i : i;
    i = (i >= n) ? (2 * n - 2 - i) : i;
    return i;
}

__device__ __forceinline__ unsigned f2sortable(float f) {
    unsigned bits = __float_as_uint(f);
    return bits ^ ((bits & 0x80000000u) ? 0xFFFFFFFFu : 0x80000000u);
}

// Native packed f16 pair: clang ext vector, no hip_fp16.h API dependence.
// __builtin_elementwise_min/max lower to v_pk_min_f16 / v_pk_max_f16.
typedef _Float16 H2 __attribute__((ext_vector_type(2)));

static __device__ __forceinline__ H2 h2min(H2 a, H2 b) { return __builtin_elementwise_min(a, b); }
static __device__ __forceinline__ H2 h2max(H2 a, H2 b) { return __builtin_elementwise_max(a, b); }

// ---- Batcher odd-even merge / sort on packed pairs (network topology
// verified rounds 2-10; unused merge outputs are DCE'd by the compiler) ----
template<int M, int N>
struct OEM {
    static __device__ __forceinline__ void run(const H2* a, const H2* b, H2* out) {
        if constexpr (M == 0) {
#pragma unroll
            for (int i = 0; i < N; ++i) out[i] = b[i];
        } else if constexpr (N == 0) {
#pragma unroll
            for (int i = 0; i < M; ++i) out[i] = a[i];
        } else if constexpr (M == 1 && N == 1) {
            out[0] = h2min(a[0], b[0]);
            out[1] = h2max(a[0], b[0]);
        } else {
            constexpr int ME = (M + 1) / 2, MO = M / 2, NE = (N + 1) / 2, NO = N / 2;
            H2 ae[ME], be[NE];
            H2 ao[MO > 0 ? MO : 1], bo[NO > 0 ? NO : 1];
#pragma unroll
            for (int i = 0; i < ME; ++i) ae[i] = a[2 * i];
#pragma unroll
            for (int i = 0; i < MO; ++i) ao[i] = a[2 * i + 1];
#pragma unroll
            for (int i = 0; i < NE; ++i) be[i] = b[2 * i];
#pragma unroll
            for (int i = 0; i < NO; ++i) bo[i] = b[2 * i + 1];
            constexpr int EL = ME + NE, OL = MO + NO;
            H2 e[EL];
            H2 o[OL > 0 ? OL : 1];
            OEM<ME, NE>::run(ae, be, e);
            OEM<MO, NO>::run(ao, bo, o);
            constexpr int P = (OL < EL - 1) ? OL : (EL - 1);
            out[0] = e[0];
#pragma unroll
            for (int i = 0; i < P; ++i) {
                out[2 * i + 1] = h2min(o[i], e[i + 1]);
                out[2 * i + 2] = h2max(o[i], e[i + 1]);
            }
            if constexpr (EL == OL)           out[M + N - 1] = o[OL - 1];
            else if constexpr (EL == OL + 2)  out[M + N - 1] = e[EL - 1];
        }
    }
};

template<int N>
struct OES {
    static __device__ __forceinline__ void run(const H2* in, H2* out) {
        if constexpr (N == 1) {
            out[0] = in[0];
        } else {
            constexpr int H = N / 2;
            H2 s1[H], s2[N - H];
            OES<H>::run(in, s1);
            OES<N - H>::run(in + H, s2);
            OEM<H, N - H>::run(s1, s2, out);
        }
    }
};

// med27 = min( M[13], min_i max(A[i], M[12-i]) ), packed over both chains
__device__ __forceinline__ H2 sel27(const H2* A, const H2* M) {
    H2 t0 = h2max(A[0], M[12]);
    H2 t1 = h2max(A[1], M[11]);
    H2 t2 = h2max(A[2], M[10]);
    H2 t3 = h2max(A[3], M[9]);
    H2 t4 = h2max(A[4], M[8]);
    H2 t5 = h2max(A[5], M[7]);
    H2 t6 = h2max(A[6], M[6]);
    H2 t7 = h2max(A[7], M[5]);
    H2 t8 = h2max(A[8], M[4]);
    H2 r0 = h2min(h2min(t0, t1), h2min(t2, t3));
    H2 r1 = h2min(h2min(t4, t5), h2min(t6, t7));
    return h2min(h2min(r0, r1), h2min(t8, M[13]));
}

// Fused: blocks 0..ZB-1 gather z0 + build global histogram (overlap with
// loss tiles, blocks ZB..ZB+NBLK-1).
__global__ __launch_bounds__(256, 4) void fused_main(const float* __restrict__ P) {
    __shared__ H2 dt[LTOTP];
    const int tid = threadIdx.x;
    const int bid = blockIdx.x;

    if (bid < ZB) {
        // ---- z0 gather + histogram role (exact f32 path, untouched) ----
        unsigned* h = (unsigned*)dt;
        for (int j = tid; j < 2048; j += 256) h[j] = 0u;
        __syncthreads();
        const int i = bid * 256 + tid;
        unsigned u = f2sortable(P[(size_t)i * NXP]);
        g_u[i] = u;
        atomicAdd(&h[u >> 21], 1u);
        __syncthreads();
        for (int j = tid; j < 2048; j += 256) {
            unsigned c = h[j];
            if (c) atomicAdd(&g_hist[j], c);
        }
        return;
    }

    // ---- loss tile role ----
    const int bf = bid - ZB;
    const int bx = bf % GX;
    const int brem = bf / GX;
    const int by = brem % GY;
    const int bz = brem / GY;
    const int x0 = bx * TX, y0 = by * TY, z0t = bz * TZ;

    // Stage packed d-tile into LDS. Entry p: xx = p%LX, rr = p/LX; low half
    // from d row y0+rr-1, high half from d row y0+rr+7 (both reflect-mapped).
    int offL[2], offH[2], lp[2];
#pragma unroll
    for (int k = 0; k < 2; ++k) {
        int p = tid + 256 * k;
        lp[k] = (p < LSLP) ? p : -1;
        if (p < LSLP) {
            int xx = p % LX, rr = p / LX;
            int gx  = refl(x0 + xx - 1, NX);
            int gyL = refl(y0 + rr - 1, NY);
            int gyH = refl(y0 + rr + 7, NY);
            offL[k] = gyL * NXP + gx;
            offH[k] = gyH * NXP + gx;
        }
    }
    for (int zz = 0; zz < LZ; ++zz) {
        int gz = refl(z0t + zz - 1, NZ);
        const float* __restrict__ pl = P + (size_t)gz * (NY * NXP);
#pragma unroll
        for (int k = 0; k < 2; ++k) {
            if (lp[k] >= 0) {
                float dL = pl[offL[k] + 1] - pl[offL[k]];
                float dH = pl[offH[k] + 1] - pl[offH[k]];
                H2 v;
                v.x = (_Float16)dL;
                v.y = (_Float16)dH;
                dt[zz * LSLP + lp[k]] = v;
            }
        }
    }
    __syncthreads();

    const int x = tid & 31;
    const int y = tid >> 5;            // 0..7; packed rows y..y+2 serve y and y+8
    const int rbase = y * LX + x;

    auto rd9 = [&](int base, H2* v) {
#pragma unroll
        for (int dy = 0; dy < 3; ++dy)
#pragma unroll
            for (int dxx = 0; dxx < 3; ++dxx)
                v[dy * 3 + dxx] = dt[base + dy * LX + dxx];
    };

    H2 S0[9], S1[9], S2[9], T[9], M[18];
    H2 c2, m2 = (H2)((_Float16)0.0f);
    const H2 one2 = (H2)((_Float16)1.0f);
    float s_acc = 0.0f;

    // Warm-up: sorted slices 0 (S0) and 1 (S1); center of slice 1.
    rd9(rbase, T);            OES<9>::run(T, S0);
    rd9(rbase + LSLP, T);     c2 = T[4];
    OES<9>::run(T, S1);

    auto accum = [&](H2 med) {
        H2 df = c2 - med;
        float dl = (float)df.x, dh = (float)df.y;
        s_acc = fmaf(dl, dl, fmaf(dh, dh, s_acc));
        m2 = h2max(m2, one2 - c2);
    };

    // Invariant at pair t: S0 = sorted slice t (oldest), S1 = sorted t+1.
    // Even step: sort t+2 -> S2, M = merge(S1,S2), A = S0.
    // Odd step:  sort t+3 -> S0 (overwrite oldest), M reused, A = S0.
    // NOT unrolled: single ~2KB body keeps the I-footprint small (R11 theory).
    int sl = rbase + 2 * LSLP;
#pragma unroll 1
    for (int t = 0; t < TZ; t += 2) {
        rd9(sl, T);
        H2 cn = T[4];
        OES<9>::run(T, S2);
        OEM<9, 9>::run(S1, S2, M);
        accum(sel27(S0, M));
        c2 = cn;
        sl += LSLP;

        rd9(sl, T);
        cn = T[4];
        OES<9>::run(T, S0);
        accum(sel27(S0, M));
        c2 = cn;
        sl += LSLP;

        // Rotate for next pair: S0' = sorted(t+2) = S2, S1' = sorted(t+3) = S0.
#pragma unroll
        for (int i = 0; i < 9; ++i) {
            H2 tmp = S0[i];
            S0[i] = S2[i];
            S1[i] = tmp;
        }
    }

    float m_acc = fmaxf((float)m2.x, (float)m2.y);

    // Block reduction -> per-block partial (plain stores, no atomics).
#pragma unroll
    for (int off = 32; off > 0; off >>= 1) {
        s_acc += __shfl_down(s_acc, off);
        m_acc = fmaxf(m_acc, __shfl_down(m_acc, off));
    }
    __shared__ float ss[4], sm[4];
    const int lane = tid & 63, wid = tid >> 6;
    if (lane == 0) { ss[wid] = s_acc; sm[wid] = m_acc; }
    __syncthreads();
    if (tid == 0) {
        float S = (ss[0] + ss[1]) + (ss[2] + ss[3]);
        float M2 = fmaxf(fmaxf(sm[0], sm[1]), fmaxf(sm[2], sm[3]));
        g_ps[bf] = (double)S;
        g_pm[bf] = M2;
    }
}

// Bucket-pick from g_hist + candidate counting-select + partial reduction.
// Re-zeroes g_hist at the end for the next call (graph-safe lifecycle).
__global__ __launch_bounds__(1024) void final_k(float* __restrict__ out) {
    __shared__ unsigned cand[2048];      // candidates, or radix hist (fallback)
    __shared__ unsigned s_cnt, s_med, s_b, s_r;
    __shared__ unsigned wsum[16], woff[16];
    const int tid = threadIdx.x;
    const int lane = tid & 63, wid = tid >> 6;
    const unsigned kk = (NZ0 - 1) / 2;   // 12287

    // ---- 1. pick the top-11-bit bucket containing rank kk ----
    unsigned h0 = g_hist[2 * tid], h1 = g_hist[2 * tid + 1];
    {
        unsigned mysum = h0 + h1, inc = mysum;
#pragma unroll
        for (int d = 1; d < 64; d <<= 1) { unsigned t2 = __shfl_up(inc, d); if (lane >= d) inc += t2; }
        if (lane == 63) wsum[wid] = inc;
        __syncthreads();
        if (tid == 0) { unsigned a = 0; for (int w = 0; w < 16; ++w) { woff[w] = a; a += wsum[w]; } }
        __syncthreads();
        unsigned exc = woff[wid] + inc - mysum;
        if (exc <= kk && kk < exc + h0) { s_b = 2u * tid; s_r = kk - exc; }
        exc += h0;
        if (exc <= kk && kk < exc + h1) { s_b = 2u * tid + 1u; s_r = kk - exc; }
    }
    __syncthreads();
    const unsigned b1 = s_b, k1 = s_r;
    // re-zero g_hist for the next call (values already consumed into regs)
    g_hist[2 * tid] = 0u; g_hist[2 * tid + 1] = 0u;

    // ---- 2. gather in-bucket candidates, exact counting-select ----
    if (tid == 0) s_cnt = 0u;
    __syncthreads();
    for (int i = tid; i < NZ0; i += 1024) {
        unsigned u = g_u[i];
        if ((u >> 21) == b1) {
            unsigned idx = atomicAdd(&s_cnt, 1u);
            if (idx < 2048u) cand[idx] = u;
        }
    }
    __syncthreads();
    const unsigned m = s_cnt;

    if (m <= 2048u) {
        for (int i = tid; i < (int)m; i += 1024) {
            unsigned c = cand[i], less = 0u, eq = 0u;
            for (unsigned j = 0; j < m; ++j) {
                unsigned v = cand[j];
                less += (v < c); eq += (v == c);
            }
            if (less <= k1 && k1 < less + eq) s_med = c;
        }
        __syncthreads();
    } else {
        // fallback: 11-bit + 10-bit radix passes over g_u (filtered)
        unsigned pref = b1, kx = k1;
        for (int j = tid; j < 2048; j += 1024) cand[j] = 0u;
        __syncthreads();
        for (int i = tid; i < NZ0; i += 1024) {
            unsigned u = g_u[i];
            if ((u >> 21) == pref) atomicAdd(&cand[(u >> 10) & 2047u], 1u);
        }
        __syncthreads();
        {
            unsigned c0 = cand[tid * 2], c1 = cand[tid * 2 + 1];
            unsigned mysum = c0 + c1, inc = mysum;
#pragma unroll
            for (int d = 1; d < 64; d <<= 1) { unsigned t2 = __shfl_up(inc, d); if (lane >= d) inc += t2; }
            if (lane == 63) wsum[wid] = inc;
            __syncthreads();
            if (tid == 0) { unsigned a = 0; for (int w = 0; w < 16; ++w) { woff[w] = a; a += wsum[w]; } }
            __syncthreads();
            unsigned exc = woff[wid] + inc - mysum;
            if (exc <= kx && kx < exc + c0) { s_b = tid * 2u; s_r = kx - exc; }
            exc += c0;
            if (exc <= kx && kx < exc + c1) { s_b = tid * 2u + 1u; s_r = kx - exc; }
        }
        __syncthreads();
        pref = (pref << 11) | s_b; kx = s_r;
        __syncthreads();
        for (int j = tid; j < 1024; j += 1024) cand[j] = 0u;
        __syncthreads();
        for (int i = tid; i < NZ0; i += 1024) {
            unsigned u = g_u[i];
            if ((u >> 10) == pref) atomicAdd(&cand[u & 1023u], 1u);
        }
        __syncthreads();
        {
            unsigned c0 = cand[tid], mysum = c0, inc = mysum;
#pragma unroll
            for (int d = 1; d < 64; d <<= 1) { unsigned t2 = __shfl_up(inc, d); if (lane >= d) inc += t2; }
            if (lane == 63) wsum[wid] = inc;
            __syncthreads();
            if (tid == 0) { unsigned a = 0; for (int w = 0; w < 16; ++w) { woff[w] = a; a += wsum[w]; } }
            __syncthreads();
            unsigned exc = woff[wid] + inc - mysum;
            if (exc <= kx && kx < exc + c0) s_b = (unsigned)tid;
        }
        __syncthreads();
        if (tid == 0) s_med = (pref << 10) | s_b;
        __syncthreads();
    }

    // ---- 3. reduce the NBLK per-block partials (fixed deterministic order) ----
    double s = 0.0; float mm = 0.0f;
    for (int i = tid; i < NBLK; i += 1024) {
        s += g_ps[i];
        mm = fmaxf(mm, g_pm[i]);
    }
#pragma unroll
    for (int off = 32; off > 0; off >>= 1) {
        s += __shfl_down(s, off);
        mm = fmaxf(mm, __shfl_down(mm, off));
    }
    __shared__ double sd[16];
    __shared__ float sf[16];
    if (lane == 0) { sd[wid] = s; sf[wid] = mm; }
    __syncthreads();
    if (tid == 0) {
        double S = 0.0; float M = 0.0f;
        for (int w = 0; w < 16; ++w) { S += sd[w]; M = fmaxf(M, sf[w]); }
        unsigned u = s_med;
        unsigned bits = (u & 0x80000000u) ? (u ^ 0x80000000u) : ~u;
        float med = __uint_as_float(bits);
        out[0] = (float)(S / (double)NVOX);
        out[1] = M;
        out[2] = med * med;
    }
}

extern "C" void kernel_launch(void* const* d_in, const int* in_sizes, int n_in,
                              void* d_out, int out_size, void* d_ws, size_t ws_size,
                              hipStream_t stream) {
    const float* P = (const float*)d_in[0];
    float* out = (float*)d_out;

    hipLaunchKernelGGL(fused_main, dim3(ZB + NBLK), dim3(256), 0, stream, P);
    hipLaunchKernelGGL(final_k, dim3(1), dim3(1024), 0, stream, out);
}